// Round 9
// baseline (319.157 us; speedup 1.0000x reference)
//
#include <hip/hip_runtime.h>
#include <math.h>

#define MM 512
#define KK 100000
#define NB1 1024               // pass1/corr blocks (4 waves each -> 4096 waves)
#define NW  (NB1 * 4)          // total waves in pass kernels
#define SSTR 32                // per-wave s stride (myN <= 25 < 32), contiguous layout
#define NVU 16                 // k_vu blocks (partial slabs)
#define NOUT 16                // k_out blocks
#define THR 0.2f               // pass1 bucket threshold: s < -THR -> plain-sum bucket

// ws float layout:
// [1024]       sumU = sum_i x_i . u
// [1025]       Z    (atomic-accumulated, raw)
// [1026]       done-counter for k_out (int)
// [1536..2048) acc (k_out cross-block accumulator)
// [2048..3072) pmax (per-block m_blk = max over E-rows of s; unconditional)
// [3072..4096) zpart (per-block Ez_blk)
// [4096..12288)    vpart[16][512] (k_vu partials, non-atomic)
// [12288..20480)   upart[16][512]
// [20480..21504)   nclipa (per-block count of P-rows, float)
// [32768..163840)  s: per-wave CONTIGUOUS, s[gw*32 + k]  (4096 waves x 32)
// [196608..720896)  Epart[b][512]: online-E partials; corr overwrites with final
// [720896..1245184) Ppart[b][512]: plain colsum of P-rows (s < -THR)
// NO memset: k_vu block 0 zeroes the scalar/counter/acc region.

__device__ inline float waveSum(float v){
  #pragma unroll
  for(int off = 32; off > 0; off >>= 1) v += __shfl_down(v, off, 64);
  return v;   // total in lane 0
}
__device__ inline float waveMax(float v){
  #pragma unroll
  for(int off = 32; off > 0; off >>= 1) v = fmaxf(v, __shfl_down(v, off, 64));
  return v;
}
__device__ inline float dot8(float4 x0, float4 x1, float4 v0, float4 v1){
  return x0.x*v0.x + x0.y*v0.y + x0.z*v0.z + x0.w*v0.w
       + x1.x*v1.x + x1.y*v1.y + x1.z*v1.z + x1.w*v1.w;
}
__device__ inline void fma4(float4& acc, float w, float4 x){
  acc.x += w * x.x; acc.y += w * x.y; acc.z += w * x.z; acc.w += w * x.w;
}
__device__ inline void add4(float4& acc, float4 x){
  acc.x += x.x; acc.y += x.y; acc.z += x.z; acc.w += x.w;
}
__device__ inline void scale4(float4& v, float s){
  v.x *= s; v.y *= s; v.z *= s; v.w *= s;
}

// Per-slab partials: vpart[b][j] = sum_{k in slab b} W[k,j] a1[k] (no atomics,
// no zero-init).  Block 0 zeroes the scalar/counter/acc region.
__global__ __launch_bounds__(512) void k_vu(const float* __restrict__ W,
                                            const float* __restrict__ a,
                                            float* __restrict__ vpart,
                                            float* __restrict__ upart,
                                            float* __restrict__ ws){
  int j  = threadIdx.x;
  int b  = blockIdx.x;
  int k0 = b * (MM / NVU);           // 32 rows per slab
  float pv = 0.f, pu = 0.f;
  #pragma unroll 8
  for(int kk = 0; kk < MM / NVU; kk++){
    float w = W[(size_t)(k0 + kk) * MM + j];
    pv += w * a[k0 + kk];
    pu += w * a[MM + k0 + kk];
  }
  vpart[b * MM + j] = pv;
  upart[b * MM + j] = pu;
  if(b == 0){
    if(j < 128) ws[1024 + j] = 0.f;   // sumU, Z, cnt, padding
    ws[1536 + j] = 0.f;               // acc
  }
}

// ---- pass1o 8-row group primitives (macros keep all indices compile-time) ----
#define LOADG(X0, X1, KB) do{                                        \
  _Pragma("unroll")                                                  \
  for(int r = 0; r < 8; r++){                                        \
    size_t row_ = (size_t)gw + (size_t)((KB) + r) * NW;              \
    const float4* xr_ = (const float4*)(x + row_ * MM);              \
    X0[r] = xr_[lane];                                               \
    X1[r] = xr_[64 + lane];                                          \
  }                                                                  \
}while(0)

#define COMPUTEG(X0, X1, KB) do{                                     \
  float d[8];                                                        \
  _Pragma("unroll")                                                  \
  for(int r = 0; r < 8; r++) d[r] = dot8(X0[r], X1[r], v0, v1);      \
  _Pragma("unroll")                                                  \
  for(int r = 0; r < 8; r += 2){                                     \
    accU0 += dot8(X0[r],   X1[r],   u0, u1);                         \
    accU1 += dot8(X0[r+1], X1[r+1], u0, u1);                         \
  }                                                                  \
  _Pragma("unroll")                                                  \
  for(int off = 1; off < 64; off <<= 1){                             \
    _Pragma("unroll")                                                \
    for(int r = 0; r < 8; r++) d[r] += __shfl_xor(d[r], off, 64);    \
  }                                                                  \
  bool pb[8];                                                        \
  float e[8];                                                        \
  _Pragma("unroll")                                                  \
  for(int r = 0; r < 8; r++){                                        \
    pb[r] = d[r] < -THR;                                             \
    e[r]  = pb[r] ? -3.4e38f : d[r];                                 \
  }                                                                  \
  float g01 = fmaxf(fmaxf(e[0], e[1]), fmaxf(e[2], e[3]));           \
  float g23 = fmaxf(fmaxf(e[4], e[5]), fmaxf(e[6], e[7]));           \
  float g   = fmaxf(g01, g23);                                       \
  if(g > m_w){                                                       \
    float sc = __expf(m_w - g);                                      \
    scale4(Ea0, sc); scale4(Ea1, sc); scale4(Eb0, sc); scale4(Eb1, sc);\
    Ez0 *= sc; Ez1 *= sc;                                            \
    m_w = g;                                                         \
  }                                                                  \
  _Pragma("unroll")                                                  \
  for(int r = 0; r < 4; r++){                                        \
    if(pb[r]){ add4(P0, X0[r]); add4(P1, X1[r]); ncl += 1.f; }       \
    else{                                                            \
      float w = __expf(d[r] - m_w); Ez0 += w;                        \
      fma4(Ea0, w, X0[r]); fma4(Ea1, w, X1[r]);                      \
    }                                                                \
  }                                                                  \
  _Pragma("unroll")                                                  \
  for(int r = 4; r < 8; r++){                                        \
    if(pb[r]){ add4(P0, X0[r]); add4(P1, X1[r]); ncl += 1.f; }       \
    else{                                                            \
      float w = __expf(d[r] - m_w); Ez1 += w;                        \
      fma4(Eb0, w, X0[r]); fma4(Eb1, w, X1[r]);                      \
    }                                                                \
  }                                                                  \
  float s0_ = (lane & 1) ? d[1] : d[0];                              \
  float s1_ = (lane & 1) ? d[3] : d[2];                              \
  float s2_ = (lane & 1) ? d[5] : d[4];                              \
  float s3_ = (lane & 1) ? d[7] : d[6];                              \
  float t0_ = (lane & 2) ? s1_ : s0_;                                \
  float t1_ = (lane & 2) ? s3_ : s2_;                                \
  float rr_ = (lane & 4) ? t1_ : t0_;                                \
  if(lane < 8) s[gw * SSTR + (KB) + lane] = rr_;                     \
}while(0)

// Pass 1 (online + bucketed, register double-buffered): per 8-row group,
// issue NEXT group's 16 float4 loads before computing the current group so
// the ~660-cycle compute body hides the L3/HBM round-trip.
//   s_i <  -THR : P += x_i (plain colsum), nclip++
//   s_i >= -THR : online E += exp(s_i - m_w) x_i (flash-style running max)
__global__ __launch_bounds__(256) void k_pass1o(const float* __restrict__ x,
                                                const float* __restrict__ vpart,
                                                const float* __restrict__ upart,
                                                float* __restrict__ s,
                                                float* __restrict__ sumU,
                                                float* __restrict__ pmax,
                                                float* __restrict__ Epart,
                                                float* __restrict__ Ppart,
                                                float* __restrict__ zpart,
                                                float* __restrict__ nclipa){
  __shared__ float lsum[4];
  __shared__ float lmax[4];
  __shared__ float ezs[4];
  __shared__ float ncs[4];
  __shared__ float lw[2048];   // 4 waves x 64 lanes x 8 cols
  __shared__ float vul[1024];  // reduced v (0..512) and u (512..1024)
  int tid  = threadIdx.x;
  int lane = tid & 63;
  int wid  = tid >> 6;
  int gw   = blockIdx.x * 4 + wid;

  // ---- prologue: reduce the 16 v/u slabs into LDS ----
  #pragma unroll
  for(int jj = 0; jj < 2; jj++){
    int j = tid + jj * 256;
    float sv = 0.f, su = 0.f;
    #pragma unroll
    for(int bb = 0; bb < NVU; bb++){
      sv += vpart[bb * MM + j];
      su += upart[bb * MM + j];
    }
    vul[j]       = sv;
    vul[512 + j] = su;
  }
  __syncthreads();

  const float4* v4 = (const float4*)vul;
  const float4* u4 = (const float4*)(vul + 512);
  float4 v0 = v4[lane],      v1 = v4[64 + lane];
  float4 u0 = u4[lane],      u1 = u4[64 + lane];
  float accU0 = 0.f, accU1 = 0.f;
  float m_w  = -3.4e38f;
  float Ez0  = 0.f, Ez1 = 0.f;
  float ncl  = 0.f;
  float4 Ea0 = make_float4(0,0,0,0), Ea1 = make_float4(0,0,0,0);
  float4 Eb0 = make_float4(0,0,0,0), Eb1 = make_float4(0,0,0,0);
  float4 P0  = make_float4(0,0,0,0), P1  = make_float4(0,0,0,0);

  int myN = (KK - 1 - gw) / NW + 1;   // rows this wave owns (24 or 25)
  int k = 0;
  if(myN >= 8){
    float4 A0[8], A1[8], B0[8], B1[8];
    LOADG(A0, A1, 0);
    bool useA = true;
    for(; k + 16 <= myN; k += 8){
      if(useA){
        LOADG(B0, B1, k + 8);       // prefetch next group
        COMPUTEG(A0, A1, k);        // compute current (hides load latency)
      } else {
        LOADG(A0, A1, k + 8);
        COMPUTEG(B0, B1, k);
      }
      useA = !useA;
    }
    if(useA) COMPUTEG(A0, A1, k);   // last full group (no prefetch)
    else     COMPUTEG(B0, B1, k);
    k += 8;
  }
  for(; k < myN; k++){
    size_t row = (size_t)gw + (size_t)k * NW;
    const float4* xr = (const float4*)(x + row * MM);
    float4 x0 = xr[lane];
    float4 x1 = xr[64 + lane];
    float d = dot8(x0, x1, v0, v1);
    accU0 += dot8(x0, x1, u0, u1);
    #pragma unroll
    for(int off = 1; off < 64; off <<= 1) d += __shfl_xor(d, off, 64);
    if(d < -THR){
      add4(P0, x0); add4(P1, x1); ncl += 1.f;
    } else {
      if(d > m_w){
        float sc = __expf(m_w - d);
        scale4(Ea0, sc); scale4(Ea1, sc); scale4(Eb0, sc); scale4(Eb1, sc);
        Ez0 *= sc; Ez1 *= sc;
        m_w = d;
      }
      float w = __expf(d - m_w);
      Ez0 += w;
      fma4(Ea0, w, x0); fma4(Ea1, w, x1);
    }
    if(lane == 0) s[gw * SSTR + k] = d;
  }

  // ---- merge split accumulators (same m_w scale) ----
  add4(Ea0, Eb0); add4(Ea1, Eb1);
  float Ez   = Ez0 + Ez1;
  float accU = accU0 + accU1;

  // ---- tail: rescale E to block max, combine E then P, write partials ----
  float us = waveSum(accU);
  if(lane == 0){ lsum[wid] = us; lmax[wid] = m_w; ncs[wid] = ncl; }
  __syncthreads();
  float m_blk = fmaxf(fmaxf(lmax[0], lmax[1]), fmaxf(lmax[2], lmax[3]));
  float sc2 = __expf(m_w - m_blk);    // wave-uniform; 0 if wave had no E-rows
  scale4(Ea0, sc2); scale4(Ea1, sc2);
  if(lane == 0) ezs[wid] = Ez * sc2;
  float4* lw4 = (float4*)lw;
  lw4[wid * 128 + lane * 2]     = Ea0;   // lane l holds cols 4l+q
  lw4[wid * 128 + lane * 2 + 1] = Ea1;   // and cols 256+4l+q
  __syncthreads();
  int l = tid >> 2, q = tid & 3;
  float o0 = lw[0*512 + l*8 + q] + lw[1*512 + l*8 + q]
           + lw[2*512 + l*8 + q] + lw[3*512 + l*8 + q];
  float o1 = lw[0*512 + l*8 + 4 + q] + lw[1*512 + l*8 + 4 + q]
           + lw[2*512 + l*8 + 4 + q] + lw[3*512 + l*8 + 4 + q];
  Epart[(size_t)blockIdx.x * 512 + tid]       = o0;
  Epart[(size_t)blockIdx.x * 512 + 256 + tid] = o1;
  __syncthreads();                    // lw fully read; safe to reuse
  lw4[wid * 128 + lane * 2]     = P0;
  lw4[wid * 128 + lane * 2 + 1] = P1;
  __syncthreads();
  float q0 = lw[0*512 + l*8 + q] + lw[1*512 + l*8 + q]
           + lw[2*512 + l*8 + q] + lw[3*512 + l*8 + q];
  float q1 = lw[0*512 + l*8 + 4 + q] + lw[1*512 + l*8 + 4 + q]
           + lw[2*512 + l*8 + 4 + q] + lw[3*512 + l*8 + 4 + q];
  Ppart[(size_t)blockIdx.x * 512 + tid]       = q0;
  Ppart[(size_t)blockIdx.x * 512 + 256 + tid] = q1;
  if(tid == 0){
    atomicAdd(sumU, lsum[0] + lsum[1] + lsum[2] + lsum[3]);
    pmax[blockIdx.x]   = m_blk;
    zpart[blockIdx.x]  = ezs[0] + ezs[1] + ezs[2] + ezs[3];
    nclipa[blockIdx.x] = ncs[0] + ncs[1] + ncs[2] + ncs[3];
  }
}

// Correction pass: compute c, M; re-read ONLY band rows where the pass1
// bucket disagrees with the true clip test: (s < -THR) XOR (s + c < 0).
// delta weight = +-(e^-M - e^(t-M)).  Fold final combine in place:
// part = Epart*scB + Ppart*e^-M + band;  Z += scB*Ez + e^-M*nclip + bandZ.
__global__ __launch_bounds__(256) void k_corr(const float* __restrict__ x,
                                              const float* __restrict__ s,
                                              const float* __restrict__ b,
                                              const float* __restrict__ a,
                                              const float* __restrict__ sumU,
                                              const float* __restrict__ pmax,
                                              float* __restrict__ Epart,
                                              const float* __restrict__ Ppart,
                                              const float* __restrict__ zpart,
                                              const float* __restrict__ nclipa,
                                              float* __restrict__ Z){
  __shared__ float red[8];
  __shared__ float czs[4];
  __shared__ float lw[2048];
  int tid  = threadIdx.x;
  int lane = tid & 63;
  int wid  = tid >> 6;
  int gw   = blockIdx.x * 4 + wid;

  // ---- prologue: c = b.(a1+a2) + sumU/K ; M = max(0, max_i s_i + c) ----
  float tp = b[tid]       * (a[tid]       + a[MM + tid])
           + b[tid + 256] * (a[tid + 256] + a[MM + tid + 256]);
  float mx = fmaxf(fmaxf(pmax[tid], pmax[tid + 256]),
                   fmaxf(pmax[tid + 512], pmax[tid + 768]));
  float wsum = waveSum(tp);
  mx = waveMax(mx);
  if(lane == 0){ red[wid] = wsum; red[4 + wid] = mx; }
  __syncthreads();
  float c  = sumU[0] * (1.0f / (float)KK) + red[0] + red[1] + red[2] + red[3];
  float mg = fmaxf(fmaxf(red[4], red[5]), fmaxf(red[6], red[7]));
  // mg is max over E-rows only; P-rows have s < -THR < mg in practice, and
  // even degenerate cases keep M >= 0 >= t for clipped rows (relu floor).
  float M  = fmaxf(0.f, mg + c);
  float eM = __expf(-M);

  // ---- band loop: rows where (s < -THR) XOR (t < 0); typically ~6-10% ----
  float4 C0 = make_float4(0,0,0,0), C1 = make_float4(0,0,0,0);
  float Cz = 0.f;
  int myN = (KK - 1 - gw) / NW + 1;
  const float4* s4 = (const float4*)(s + gw * SSTR);
  #pragma unroll
  for(int g2 = 0; g2 < 7; g2++){
    int kb = g2 * 4;
    if(kb >= myN) break;
    float4 sv = s4[g2];
    float svv[4] = {sv.x, sv.y, sv.z, sv.w};
    #pragma unroll
    for(int r = 0; r < 4; r++){
      int k = kb + r;
      float si = svv[r];
      float t  = si + c;
      bool pb  = si < -THR;     // pass1 bucket: plain-sum
      bool cl  = t  < 0.f;      // true clip
      if(k < myN && (pb != cl)){
        // pass1-assigned weight: pb ? e^-M : e^(t-M); true: cl ? e^-M : e^(t-M)
        float d  = eM - __expf(t - M);
        float kap = cl ? d : -d;
        size_t row = (size_t)gw + (size_t)k * NW;
        const float4* xr = (const float4*)(x + row * MM);
        float4 x0 = xr[lane], x1 = xr[64 + lane];
        fma4(C0, kap, x0); fma4(C1, kap, x1); Cz += kap;
      }
    }
  }

  // ---- combine band C across waves; fold final partial in place; Z ----
  __syncthreads();                 // red fully consumed above
  float4* lw4 = (float4*)lw;
  lw4[wid * 128 + lane * 2]     = C0;
  lw4[wid * 128 + lane * 2 + 1] = C1;
  if(lane == 0) czs[wid] = Cz;     // Cz identical across lanes (uniform kap)
  __syncthreads();
  int l = tid >> 2, q = tid & 3;
  float o0 = lw[0*512 + l*8 + q] + lw[1*512 + l*8 + q]
           + lw[2*512 + l*8 + q] + lw[3*512 + l*8 + q];
  float o1 = lw[0*512 + l*8 + 4 + q] + lw[1*512 + l*8 + 4 + q]
           + lw[2*512 + l*8 + 4 + q] + lw[3*512 + l*8 + 4 + q];
  float scB = __expf(c - M + pmax[blockIdx.x]);   // <= 1 by construction
  size_t base = (size_t)blockIdx.x * 512;
  Epart[base + tid]       = Epart[base + tid]       * scB
                          + Ppart[base + tid]       * eM + o0;
  Epart[base + 256 + tid] = Epart[base + 256 + tid] * scB
                          + Ppart[base + 256 + tid] * eM + o1;
  if(tid == 0)
    atomicAdd(Z, czs[0] + czs[1] + czs[2] + czs[3]
                 + scB * zpart[blockIdx.x] + eM * nclipa[blockIdx.x]);
}

// Reduce part[1024][512] -> acc, last block divides by Z and writes out.
__global__ __launch_bounds__(256) void k_out(const float* __restrict__ part,
                                             float* __restrict__ acc,
                                             const float* __restrict__ Z,
                                             int* __restrict__ cnt,
                                             float* __restrict__ out){
  __shared__ int lastf;
  int tid = threadIdx.x;
  const float* p = part + (size_t)blockIdx.x * (NB1 / NOUT) * 512;
  float s0 = 0.f, s1 = 0.f;
  #pragma unroll 8
  for(int bb = 0; bb < NB1 / NOUT; bb++){
    s0 += p[bb * 512 + tid];
    s1 += p[bb * 512 + 256 + tid];
  }
  atomicAdd(&acc[tid],       s0);
  atomicAdd(&acc[tid + 256], s1);
  __threadfence();
  if(tid == 0) lastf = (atomicAdd(cnt, 1) == NOUT - 1) ? 1 : 0;
  __syncthreads();
  if(lastf){
    float z = Z[0];   // written by previous dispatch — safe plain read
    float v0 = atomicAdd(&acc[tid],       0.0f);  // coherent read of atomics
    float v1 = atomicAdd(&acc[tid + 256], 0.0f);
    out[tid]       = v0 / z;
    out[tid + 256] = v1 / z;
  }
}

extern "C" void kernel_launch(void* const* d_in, const int* in_sizes, int n_in,
                              void* d_out, int out_size, void* d_ws, size_t ws_size,
                              hipStream_t stream) {
  const float* x = (const float*)d_in[0];
  const float* W = (const float*)d_in[1];
  const float* b = (const float*)d_in[2];
  const float* a = (const float*)d_in[3];
  float* ws  = (float*)d_ws;
  float* out = (float*)d_out;

  float* sumU   = ws + 1024;
  float* Z      = ws + 1025;
  int*   cnt    = (int*)(ws + 1026);
  float* acc    = ws + 1536;
  float* pmax   = ws + 2048;
  float* zpart  = ws + 3072;
  float* vpart  = ws + 4096;
  float* upart  = ws + 12288;
  float* nclipa = ws + 20480;
  float* s      = ws + 32768;
  float* Epart  = ws + 196608;
  float* Ppart  = ws + 720896;

  k_vu    <<<NVU,  512, 0, stream>>>(W, a, vpart, upart, ws);
  k_pass1o<<<NB1,  256, 0, stream>>>(x, vpart, upart, s, sumU, pmax,
                                     Epart, Ppart, zpart, nclipa);
  k_corr  <<<NB1,  256, 0, stream>>>(x, s, b, a, sumU, pmax,
                                     Epart, Ppart, zpart, nclipa, Z);
  k_out   <<<NOUT, 256, 0, stream>>>(Epart, acc, Z, cnt, out);
}